// Round 7
// baseline (295.525 us; speedup 1.0000x reference)
//
#include <hip/hip_runtime.h>

#define NPIX (512 * 512)  // 262144
#define NB 32
#define NK 4
#define TPB 256
#define CPB 64                      // chunks per image / per (b,k)
#define CHUNK (NPIX / CPB)          // 4096 elems
#define T4PT (CHUNK / (TPB * 4))    // 4 float4 per thread per input
#define GPB 16                      // chunk-groups per (b,k)
#define CPG (CPB / GPB)             // 4 chunks per block

// ws layout (floats):
// [0..127]   focal_sum  (b*4+k)
// [128..255] p_sum
// [256..383] inter
// [384..511] m_sum
// [512..639] mi
// [640..671] t_sum (per b)
// [672]      completion counter (int view)
#define TSUM_OFF (5 * NB * NK)
#define CNT_OFF 672
#define WS_FLOATS 673

__device__ __forceinline__ float area_lo(int k) {
  return k == 0 ? 0.04f : (k == 1 ? 0.0f : (k == 2 ? 0.01f : 0.16f));
}
__device__ __forceinline__ float area_hi(int k) {
  return k == 0 ? 0.64f : (k == 1 ? 0.04f : (k == 2 ? 0.25f : 1.0f));
}
__device__ __forceinline__ float ld_agent(const float* p) {
  // coherent (agent-scope) load: bypasses possibly-stale per-XCD L2 lines
  return __hip_atomic_load(p, __ATOMIC_RELAXED, __HIP_MEMORY_SCOPE_AGENT);
}

// ---- t_sum pre-scan: 32 MB, exact integer sums ----
__global__ __launch_bounds__(TPB, 8) void sam_loss_tsum(
    const float* __restrict__ t, float* __restrict__ ws) {
  const int blk = blockIdx.x;  // b*CPB + c
  const int b = blk >> 6;
  const int c = blk & (CPB - 1);
  const float4* __restrict__ t4 =
      (const float4*)(t + (size_t)b * NPIX + (size_t)c * CHUNK);
  float ts = 0.f;
#pragma unroll
  for (int it = 0; it < T4PT; ++it) {
    const float4 tv = t4[it * TPB + threadIdx.x];
    ts += (tv.x + tv.y) + (tv.z + tv.w);
  }
#pragma unroll
  for (int off = 32; off > 0; off >>= 1) ts += __shfl_down(ts, off, 64);
  __shared__ float red[TPB / 64];
  const int lane = threadIdx.x & 63;
  const int wid = threadIdx.x >> 6;
  if (lane == 0) red[wid] = ts;
  __syncthreads();
  if (threadIdx.x == 0) {
    atomicAdd(ws + TSUM_OFF + b, red[0] + red[1] + red[2] + red[3]);
  }
}

// ---- main: 2048 fat blocks, validity-gated, fused finalization ----
__global__ __launch_bounds__(TPB, 8) void sam_loss_main(
    const float* __restrict__ x, const float* __restrict__ t,
    const float* __restrict__ ious, float* __restrict__ ws,
    float* __restrict__ out) {
  // blockIdx bits: [0:2]=bg_low (XCD lane), [3:4]=k, [5:10]=bg_high.
  // The 4 k-siblings of one (b,g) differ by 8/16/24 -> same XCD -> t reuse.
  const int i = blockIdx.x;
  const int bg = ((i >> 5) << 3) | (i & 7);  // b*GPB + g, in [0,512)
  const int k = (i >> 3) & 3;
  const int b = bg >> 4;
  const int g = bg & (GPB - 1);

  // validity gate (uniform per block); tsum from prior kernel is visible
  const float tsum = ws[TSUM_OFF + b];
  const float ratio = tsum * (1.0f / (float)NPIX);
  const bool valid = (ratio > area_lo(k)) && (ratio < area_hi(k));

  const int lane = threadIdx.x & 63;
  const int wid = threadIdx.x >> 6;
  __shared__ float red[TPB / 64][5];
  __shared__ int islast;

  if (valid) {
    const float* tb = t + (size_t)b * NPIX + (size_t)(g * CPG) * CHUNK;
    const float* xb = x + ((size_t)b * NK + k) * NPIX + (size_t)(g * CPG) * CHUNK;

    float fs = 0.f, ps = 0.f, is_ = 0.f, ms = 0.f, mi = 0.f;
#pragma unroll 1
    for (int j = 0; j < CPG; ++j) {
      const float4* __restrict__ t4 = (const float4*)(tb + j * CHUNK);
      const float4* __restrict__ x4 = (const float4*)(xb + j * CHUNK);
      // issue all 8 loads of this chunk up front
      float4 xv[T4PT], tv[T4PT];
#pragma unroll
      for (int it = 0; it < T4PT; ++it) {
        const int idx = it * TPB + threadIdx.x;
        xv[it] = x4[idx];
        tv[it] = t4[idx];
      }
#pragma unroll
      for (int it = 0; it < T4PT; ++it) {
        const float xx[4] = {xv[it].x, xv[it].y, xv[it].z, xv[it].w};
        const float tt[4] = {tv[it].x, tv[it].y, tv[it].z, tv[it].w};
#pragma unroll
        for (int jj = 0; jj < 4; ++jj) {
          const float xf = xx[jj];
          const float tf = tt[jj];  // exactly 0.0 or 1.0
          const float ax = fabsf(xf);
          const float e = __expf(-ax);                      // exp(-|x|)
          const float denom = 1.0f + e;
          const float r = __builtin_amdgcn_rcpf(denom);     // sigmoid(|x|)
          const float l1 = __logf(denom);                   // log1p(e)
          const float er = e * r;                           // sigmoid(-|x|)
          const bool pos = xf >= 0.0f;
          const bool tpos = tf != 0.0f;
          const bool mx = pos != tpos;
          const float bce = (mx ? ax : 0.0f) + l1;          // t?sp(-x):sp(x)
          const float om = mx ? r : er;                     // 1 - exp(-bce)
          fs = fmaf(om * om, bce, fs);
          const float sp = pos ? r : er;                    // sigmoid(x)
          ps += sp;
          is_ = fmaf(sp, tf, is_);
          const float mf = pos ? 1.0f : 0.0f;
          ms += mf;
          mi = fmaf(mf, tf, mi);
        }
      }
    }

    float vals[5] = {fs, ps, is_, ms, mi};
#pragma unroll
    for (int j = 0; j < 5; ++j) {
      float v = vals[j];
#pragma unroll
      for (int off = 32; off > 0; off >>= 1) v += __shfl_down(v, off, 64);
      if (lane == 0) red[wid][j] = v;
    }
    __syncthreads();
    if (threadIdx.x < 5) {
      const int j = threadIdx.x;
      const float v = red[0][j] + red[1][j] + red[2][j] + red[3][j];
      atomicAdd(ws + j * (NB * NK) + b * NK + k, v);
    }
  }

  // completion counter; last block runs the finalization
  if (threadIdx.x == 0) {
    __threadfence();
    const int old = atomicAdd((int*)ws + CNT_OFF, 1);
    islast = (old == (int)gridDim.x - 1);
  }
  __syncthreads();
  if (!islast || threadIdx.x >= 64) return;

  // ---- fused pass2 on wave 0 of the last block ----
  const float S = 1e-4f;
  float pf = 0.f, pd = 0.f, pi = 0.f, sv = 0.f;
  if (lane < NB) {
    const int bb = lane;
    const float tsum2 = ld_agent(ws + TSUM_OFF + bb);
    const float ratio2 = tsum2 * (1.0f / (float)NPIX);
    float cnt = 0.f, sf = 0.f, sd = 0.f, si = 0.f;
#pragma unroll
    for (int kk = 0; kk < NK; ++kk) {
      const bool v2 = (ratio2 > area_lo(kk)) && (ratio2 < area_hi(kk));
      if (v2) {
        const int idx = bb * NK + kk;
        const float focal = 0.8f * ld_agent(ws + idx) / (float)NPIX;
        const float psum = ld_agent(ws + 1 * (NB * NK) + idx);
        const float inter = ld_agent(ws + 2 * (NB * NK) + idx);
        const float msum = ld_agent(ws + 3 * (NB * NK) + idx);
        const float mi2 = ld_agent(ws + 4 * (NB * NK) + idx);
        const float dice = 1.0f - (2.0f * inter + S) / (psum + tsum2 + S);
        const float iou_gt = (mi2 + S) / (msum + tsum2 - mi2 + S);
        const float d = ious[idx] - iou_gt;
        cnt += 1.0f;
        sf += focal;
        sd += dice;
        si += d * d;
      }
    }
    if (cnt > 0.f) {
      pf = sf / cnt;
      pd = sd / cnt;
      pi = si / cnt;
      sv = 1.0f;
    }
  }
#pragma unroll
  for (int off = 32; off > 0; off >>= 1) {
    pf += __shfl_down(pf, off, 64);
    pd += __shfl_down(pd, off, 64);
    pi += __shfl_down(pi, off, 64);
    sv += __shfl_down(sv, off, 64);
  }
  if (lane == 0) {
    const float inv = sv > 0.f ? 1.0f / sv : 1.0f;
    out[0] = 20.0f * pf * inv;
    out[1] = pd * inv;
    out[2] = pi * inv;
  }
}

extern "C" void kernel_launch(void* const* d_in, const int* in_sizes, int n_in,
                              void* d_out, int out_size, void* d_ws,
                              size_t ws_size, hipStream_t stream) {
  const float* pred_masks = (const float*)d_in[0];
  const float* pred_ious = (const float*)d_in[1];
  const float* targets = (const float*)d_in[2];
  float* out = (float*)d_out;
  float* ws = (float*)d_ws;

  hipMemsetAsync(ws, 0, WS_FLOATS * sizeof(float), stream);
  sam_loss_tsum<<<NB * CPB, TPB, 0, stream>>>(targets, ws);
  sam_loss_main<<<NB * NK * GPB, TPB, 0, stream>>>(pred_masks, targets,
                                                   pred_ious, ws, out);
}